// Round 18
// baseline (721.883 us; speedup 1.0000x reference)
//
#include <hip/hip_runtime.h>
#include <hip/hip_cooperative_groups.h>

namespace cg = cooperative_groups;

typedef __bf16 bf16x8 __attribute__((ext_vector_type(8)));
typedef float  floatx4 __attribute__((ext_vector_type(4)));

constexpr int B_    = 2048;
constexpr int NIN   = 256;
constexpr int H_    = 128;
constexpr int RANK_ = 8;
constexpr float EPS_ = 1e-5f;

// ---------------------------------------------------------------------------
// HEAD: zero stats; balanced in_proj (1024 blocks, 2 rows each); pconv.
// (verified at 283.9/275.2 runs; k_head itself 43 µs, not this round's target)
__global__ __launch_bounds__(256)
void k_head(const float* __restrict__ X,
            const float* __restrict__ W1, const float* __restrict__ b1,
            const float* __restrict__ W2, const float* __restrict__ b2,
            const float* __restrict__ P,
            float* __restrict__ R2, __bf16* __restrict__ Zbf,
            __bf16* __restrict__ Pperm, float* __restrict__ stats /* 9*256 */) {
    __shared__ float smem[4160];             // sx[512] / sT[32*129]
    const int bx = blockIdx.x, t = threadIdx.x;

    if (bx < RANK_ + 1) stats[bx * 256 + t] = 0.f;

    {   // in_proj rows bx*2, bx*2+1; thread (col,rh) -> row rh
        const int b0 = bx * 2;
#pragma unroll
        for (int i = 0; i < 2; ++i) {
            const int e = i * 256 + t;
            smem[e] = X[(size_t)(b0 + (e >> 8)) * NIN + (e & 255)];
        }
        __syncthreads();
        const int col = t & 127, rh = t >> 7;
        float s1 = 0.f, s2 = 0.f;
        const float* sx = smem + rh * 256;
#pragma unroll 16
        for (int i = 0; i < NIN; ++i) {
            const float w1 = W1[i * H_ + col];
            const float w2 = W2[i * H_ + col];
            s1 = fmaf(sx[i], w1, s1);  s2 = fmaf(sx[i], w2, s2);
        }
        const int br = b0 + rh;
        const float z = fmaxf(s1 + b1[col], 0.f), r = fmaxf(s2 + b2[col], 0.f);
        Zbf[(size_t)br * H_ + col] = (__bf16)z;  R2[(size_t)br * H_ + col] = r;
        __syncthreads();
    }
    {   // pconv: unit = bx -> (rank r, p); up-front loads + LDS transpose
        const int r = bx >> 7, p = bx & 127;
        const float4* Pp4 = (const float4*)(P + ((size_t)r * H_ + p) * (H_ * H_));
        __bf16* dst = Pperm + (size_t)r * (H_ * H_ * H_);
        const int L = t & 63, quad = L >> 4, lo = L & 15, g0 = t >> 6;

        float4 rg[4][4];                     // all 16 loads in flight at once
#pragma unroll
        for (int s = 0; s < 4; ++s)
#pragma unroll
            for (int it = 0; it < 4; ++it) {
                const int idx = it * 256 + t;
                rg[s][it] = Pp4[(size_t)(s * 32 + (idx >> 5)) * 32 + (idx & 31)];
            }
#pragma unroll
        for (int s = 0; s < 4; ++s) {
            if (s) __syncthreads();
#pragma unroll
            for (int it = 0; it < 4; ++it) {
                const int idx = it * 256 + t;
                float* d = smem + (idx >> 5) * 129 + (idx & 31) * 4;
                d[0] = rg[s][it].x; d[1] = rg[s][it].y;
                d[2] = rg[s][it].z; d[3] = rg[s][it].w;
            }
            __syncthreads();
#pragma unroll
            for (int gg = 0; gg < 2; ++gg) {  // conflict-free reads, emit 16B
                const int g = g0 + 4 * gg;
                __bf16 v8[8];
#pragma unroll
                for (int j = 0; j < 8; ++j)
                    v8[j] = (__bf16)smem[(quad * 8 + j) * 129 + g * 16 + lo];
                *(bf16x8*)(dst + (((size_t)(g * 128 + p) * 4 + s) * 64 + L) * 8) =
                    *(const bf16x8*)v8;
            }
        }
    }
}

// ---------------------------------------------------------------------------
// ALL 8 RANKS in one cooperative kernel. Grid (8 kg, 32 m) = 256 blocks =
// 1 block/CU (co-residency guaranteed), 512 thr, launch_bounds(512,2) ->
// VGPR<=256 (round-1 body compiled cleanly here; no spill risk).
// Body per rank = the harness-verified round-1 k_rank (64-row m-tiles,
// 4-deep cyclic B pipeline, zero-C MFMA, setprio). Ranks separated by
// __threadfence() + grid.sync(); stats via device-scope atomics (zeroed by
// k_head). A-frags loaded ONCE (rank-invariant). Kills 7 launch/drain
// boundaries AND makes the rank chain one big dispatch -> full rocprof
// counters finally visible.
__global__ __launch_bounds__(512, 2)
void k_ranks(const __bf16* __restrict__ Pperm, const __bf16* __restrict__ Zbf,
             const float* __restrict__ gz, const float* __restrict__ bz,
             float* __restrict__ T, float* __restrict__ stats) {
    __shared__ float smem[8960];     // sZin[128][68] | reduce[8*1024]+cs; sAl/sBe tail
    const int kg = blockIdx.x, mblk = blockIdx.y, b0 = mblk * 64;
    const int t = threadIdx.x;
    const int w = t >> 6, L = t & 63, quad = L >> 4, lo = L & 15;
    float* sAl = smem + 8704; float* sBe = smem + 8832;

    // A-frags: 64 rows x K=128, rank-invariant (64 VGPRs) — loaded once.
    bf16x8 A[4][4];
#pragma unroll
    for (int mt = 0; mt < 4; ++mt)
#pragma unroll
        for (int ks = 0; ks < 4; ++ks)
            A[mt][ks] = *(const bf16x8*)(Zbf + (size_t)(b0 + mt * 16 + lo) * H_ + ks * 32 + quad * 8);

    const int p0 = w * 16;
    const size_t fbase = ((size_t)kg * 128 + p0) * 4;
    cg::grid_group grid = cg::this_grid();

    for (int r = 0; r < RANK_; ++r) {
        const bf16x8* Pb = (const bf16x8*)(Pperm + (size_t)r * (H_ * H_ * H_));
        const float* prevT = T + (size_t)(r - 1) * B_ * H_;   // unused when r==0
        float* Tr = T + (size_t)r * B_ * H_;
        float* statsr = stats + r * 256;

#define LOADB(dst, pl) do {                                                   \
    _Pragma("unroll") for (int s_ = 0; s_ < 4; ++s_)                          \
        dst[s_] = Pb[(fbase + (size_t)(pl) * 4 + s_) * 64 + L];               \
} while (0)

        // 4 pipeline stages issued before staging: 16 loads in flight; cold
        // L2 latency hides under the zin staging phase below.
        bf16x8 B0[4], B1[4], B2[4], B3[4];
        LOADB(B0, 0);
        LOADB(B1, 1);
        LOADB(B2, 2);
        LOADB(B3, 3);

        if (r && t < 128) {
            const float s1 = stats[(r - 1) * 256 + t], s2 = stats[(r - 1) * 256 + 128 + t];
            const float mm = s1 * (1.f / B_);
            const float var = s2 * (1.f / B_) - mm * mm;
            const float a = rsqrtf(var + EPS_) * gz[t];
            sAl[t] = a; sBe[t] = bz[t] - mm * a;
        }
        __syncthreads();
        {   // stage zin -> sZin[p][row] (stride 68), 64 rows
            const int sp = t & 127, rr = t >> 7;     // col, row-quarter
            if (r == 0) {
#pragma unroll
                for (int i = 0; i < 16; ++i) {
                    const int row = rr + 4 * i;
                    smem[sp * 68 + row] = (float)Zbf[(size_t)(b0 + row) * H_ + sp];
                }
            } else {
                const float a = sAl[sp], be = sBe[sp];
#pragma unroll
                for (int i = 0; i < 16; ++i) {
                    const int row = rr + 4 * i;
                    smem[sp * 68 + row] = fmaf(prevT[(size_t)(b0 + row) * H_ + sp], a, be);
                }
            }
        }
        __syncthreads();

        floatx4 acc[4];
#pragma unroll
        for (int mt = 0; mt < 4; ++mt) acc[mt] = (floatx4){0.f, 0.f, 0.f, 0.f};

#define COMPUTE(Bx, pg) do {                                                  \
    floatx4 S_[4];                                                            \
    __builtin_amdgcn_s_setprio(1);                                            \
    _Pragma("unroll") for (int mt_ = 0; mt_ < 4; ++mt_)                       \
        S_[mt_] = __builtin_amdgcn_mfma_f32_16x16x32_bf16(                    \
            A[mt_][0], Bx[0], (floatx4){0.f, 0.f, 0.f, 0.f}, 0, 0, 0);        \
    _Pragma("unroll") for (int ks_ = 1; ks_ < 4; ++ks_)                       \
        _Pragma("unroll") for (int mt_ = 0; mt_ < 4; ++mt_)                   \
            S_[mt_] = __builtin_amdgcn_mfma_f32_16x16x32_bf16(                \
                A[mt_][ks_], Bx[ks_], S_[mt_], 0, 0, 0);                      \
    __builtin_amdgcn_s_setprio(0);                                            \
    _Pragma("unroll") for (int mt_ = 0; mt_ < 4; ++mt_) {                     \
        const floatx4 zi_ =                                                   \
            *(const floatx4*)&smem[(pg) * 68 + mt_ * 16 + quad * 4];          \
        acc[mt_] += zi_ * S_[mt_];                                            \
    }                                                                         \
} while (0)

#pragma unroll
        for (int pp = 0; pp < 16; pp += 4) {
            COMPUTE(B0, p0 + pp);     if (pp < 12) LOADB(B0, pp + 4);
            COMPUTE(B1, p0 + pp + 1); if (pp < 12) LOADB(B1, pp + 5);
            COMPUTE(B2, p0 + pp + 2); if (pp < 12) LOADB(B2, pp + 6);
            COMPUTE(B3, p0 + pp + 3); if (pp < 12) LOADB(B3, pp + 7);
        }
#undef LOADB
#undef COMPUTE

        __syncthreads();             // sZin dead; reuse for cross-wave p-reduce
#pragma unroll
        for (int mt = 0; mt < 4; ++mt)
#pragma unroll
            for (int i = 0; i < 4; ++i)
                smem[w * 1024 + (mt * 4 + i) * 64 + L] = acc[mt][i];
        if (t < 32) smem[8192 + t] = 0.f;
        __syncthreads();

        float cs = 0.f, cs2 = 0.f;
#pragma unroll
        for (int k2 = 0; k2 < 2; ++k2) {
            const int e = t + 512 * k2;
            float v = 0.f;
#pragma unroll
            for (int q = 0; q < 8; ++q) v += smem[q * 1024 + e];
            const int j = e >> 6, L2 = e & 63;
            const int row = b0 + (j >> 2) * 16 + (L2 >> 4) * 4 + (j & 3);
            const int col = kg * 16 + (L2 & 15);
            Tr[(size_t)row * H_ + col] = v;
            cs += v; cs2 += v * v;
        }
        cs  += __shfl_xor(cs, 16);  cs  += __shfl_xor(cs, 32);
        cs2 += __shfl_xor(cs2, 16); cs2 += __shfl_xor(cs2, 32);
        if (L < 16) { atomicAdd(&smem[8192 + L], cs); atomicAdd(&smem[8208 + L], cs2); }
        __syncthreads();
        if (t < 16)      atomicAdd(&statsr[kg * 16 + t],            smem[8192 + t]);
        else if (t < 32) atomicAdd(&statsr[128 + kg * 16 + t - 16], smem[8192 + t]);

        if (r < RANK_ - 1) {
            __threadfence();         // T_r + stats_r visible device-wide
            grid.sync();
        }
    }
}

// ---------------------------------------------------------------------------
// Y = (1/8) sum_r BN_r(T_r); ystats. Grid 64 x 256.
__global__ __launch_bounds__(256)
void k_y(const float* __restrict__ T, const float* __restrict__ sums,
         const float* __restrict__ gz, const float* __restrict__ bz,
         float* __restrict__ Y, float* __restrict__ ysums) {
    __shared__ float al[1024], be[1024], red[256];
    const int bx = blockIdx.x, t = threadIdx.x;
    for (int e = t; e < 1024; e += 256) {
        const int rr = e >> 7, k = e & 127;
        const float s1 = sums[rr * 256 + k], s2 = sums[rr * 256 + 128 + k];
        const float mm = s1 * (1.f / B_);
        const float var = s2 * (1.f / B_) - mm * mm;
        const float a = rsqrtf(var + EPS_) * gz[k];
        al[e] = a; be[e] = bz[k] - mm * a;
    }
    red[t] = 0.f;
    __syncthreads();
    const int col = t & 127, half = t >> 7;
    float ps = 0.f, ps2 = 0.f;
    for (int i = 0; i < 16; ++i) {
        const int b = bx * 32 + half + 2 * i;
        float y = 0.f;
#pragma unroll
        for (int rr = 0; rr < 8; ++rr)
            y += fmaf(T[(size_t)rr * B_ * H_ + (size_t)b * H_ + col],
                      al[rr * 128 + col], be[rr * 128 + col]);
        y *= (1.f / RANK_);
        Y[(size_t)b * H_ + col] = y;
        ps += y; ps2 += y * y;
    }
    atomicAdd(&red[col],       half == 0 ? ps  : 0.f);
    atomicAdd(&red[128 + col], half == 0 ? ps2 : 0.f);
    __syncthreads();
    atomicAdd(&red[col],       half == 1 ? ps  : 0.f);
    atomicAdd(&red[128 + col], half == 1 ? ps2 : 0.f);
    __syncthreads();
    if (t < 128) {
        atomicAdd(&ysums[t],       red[t]);
        atomicAdd(&ysums[128 + t], red[128 + t]);
    }
}

// ---------------------------------------------------------------------------
// out = relu(relu(BN(Y)@W3 + b3) + R2). Grid 256 x 256, 8 rows per block.
__global__ __launch_bounds__(256)
void k_out(const float* __restrict__ Y, const float* __restrict__ ystats,
           const float* __restrict__ gy, const float* __restrict__ by,
           const float* __restrict__ W3, const float* __restrict__ b3,
           const float* __restrict__ R2, float* __restrict__ out) {
    __shared__ float sy[8 * 132];
    const int bx = blockIdx.x, t = threadIdx.x;
    const int col = t & 127, rh = t >> 7;
    const int b0 = bx * 8;
    const float mm = ystats[col] * (1.f / B_);
    const float var = ystats[128 + col] * (1.f / B_) - mm * mm;
    const float ay = rsqrtf(var + EPS_) * gy[col];
    const float bb = by[col] - mm * ay;
#pragma unroll
    for (int i = 0; i < 4; ++i) {
        const int row = rh + 2 * i;
        sy[row * 132 + col] = fmaf(Y[(size_t)(b0 + row) * H_ + col], ay, bb);
    }
    __syncthreads();
#pragma unroll
    for (int j = 0; j < 4; ++j) {
        const int row = rh * 4 + j;
        float s = 0.f;
        const float* syr = sy + row * 132;
#pragma unroll 8
        for (int h = 0; h < H_; ++h)
            s = fmaf(syr[h], W3[h * H_ + col], s);
        const size_t gi = (size_t)(b0 + row) * H_ + col;
        out[gi] = fmaxf(fmaxf(s + b3[col], 0.f) + R2[gi], 0.f);
    }
}

// ---------------------------------------------------------------------------
extern "C" void kernel_launch(void* const* d_in, const int* in_sizes, int n_in,
                              void* d_out, int out_size, void* d_ws, size_t ws_size,
                              hipStream_t stream) {
    const float* X  = (const float*)d_in[0];
    const float* W1 = (const float*)d_in[1];
    const float* b1 = (const float*)d_in[2];
    const float* W2 = (const float*)d_in[3];
    const float* b2 = (const float*)d_in[4];
    const float* W3 = (const float*)d_in[5];
    const float* b3 = (const float*)d_in[6];
    const float* P  = (const float*)d_in[7];
    const float* gz = (const float*)d_in[8];
    const float* bz = (const float*)d_in[9];
    const float* gy = (const float*)d_in[10];
    const float* by = (const float*)d_in[11];
    float* out = (float*)d_out;

    char* wsb = (char*)d_ws;
    float* R2     = (float*)wsb;   wsb += (size_t)B_ * H_ * 4;
    float* Y      = (float*)wsb;   wsb += (size_t)B_ * H_ * 4;
    float* stats  = (float*)wsb;   wsb += (size_t)(RANK_ + 1) * 256 * 4;  // sums | ysums
    float* T      = (float*)wsb;   wsb += (size_t)RANK_ * B_ * H_ * 4;
    __bf16* Zbf   = (__bf16*)wsb;  wsb += (size_t)B_ * H_ * 2;
    __bf16* Pperm = (__bf16*)wsb;

    float* ysums = stats + RANK_ * 256;

    k_head<<<1024, 256, 0, stream>>>(X, W1, b1, W2, b2, P, R2, Zbf, Pperm, stats);

    {
        const __bf16* Pperm_c = Pperm;
        const __bf16* Zbf_c   = Zbf;
        const float*  gz_c    = gz;
        const float*  bz_c    = bz;
        float*        T_c     = T;
        float*        stats_c = stats;
        void* kargs[6] = { (void*)&Pperm_c, (void*)&Zbf_c, (void*)&gz_c,
                           (void*)&bz_c, (void*)&T_c, (void*)&stats_c };
        hipLaunchCooperativeKernel((void*)k_ranks, dim3(8, 32), dim3(512),
                                   kargs, 0, stream);
    }

    k_y<<<64, 256, 0, stream>>>(T, stats, gz, bz, Y, ysums);
    k_out<<<256, 256, 0, stream>>>(Y, ysums, gy, by, W3, b3, R2, out);
}

// Round 19
// 285.545 us; speedup vs baseline: 2.5281x; 2.5281x over previous
//
#include <hip/hip_runtime.h>

typedef __bf16 bf16x8 __attribute__((ext_vector_type(8)));
typedef float  floatx4 __attribute__((ext_vector_type(4)));

constexpr int B_    = 2048;
constexpr int NIN   = 256;
constexpr int H_    = 128;
constexpr int RANK_ = 8;
constexpr float EPS_ = 1e-5f;

// ---------------------------------------------------------------------------
// HEAD: zero ysums (stats rows); balanced in_proj (1024 blocks, 2 rows); pconv.
__global__ __launch_bounds__(256)
void k_head(const float* __restrict__ X,
            const float* __restrict__ W1, const float* __restrict__ b1,
            const float* __restrict__ W2, const float* __restrict__ b2,
            const float* __restrict__ P,
            float* __restrict__ R2, __bf16* __restrict__ Zbf,
            __bf16* __restrict__ Pperm, float* __restrict__ stats /* 9*256 */) {
    __shared__ float smem[4160];             // sx[512] / sT[32*129]
    const int bx = blockIdx.x, t = threadIdx.x;

    if (bx < RANK_ + 1) stats[bx * 256 + t] = 0.f;

    {   // in_proj rows bx*2, bx*2+1; thread (col,rh) -> row rh
        const int b0 = bx * 2;
#pragma unroll
        for (int i = 0; i < 2; ++i) {
            const int e = i * 256 + t;
            smem[e] = X[(size_t)(b0 + (e >> 8)) * NIN + (e & 255)];
        }
        __syncthreads();
        const int col = t & 127, rh = t >> 7;
        float s1 = 0.f, s2 = 0.f;
        const float* sx = smem + rh * 256;
#pragma unroll 16
        for (int i = 0; i < NIN; ++i) {
            const float w1 = W1[i * H_ + col];
            const float w2 = W2[i * H_ + col];
            s1 = fmaf(sx[i], w1, s1);  s2 = fmaf(sx[i], w2, s2);
        }
        const int br = b0 + rh;
        const float z = fmaxf(s1 + b1[col], 0.f), r = fmaxf(s2 + b2[col], 0.f);
        Zbf[(size_t)br * H_ + col] = (__bf16)z;  R2[(size_t)br * H_ + col] = r;
        __syncthreads();
    }
    {   // pconv: unit = bx -> (rank r, p); up-front loads + LDS transpose
        const int r = bx >> 7, p = bx & 127;
        const float4* Pp4 = (const float4*)(P + ((size_t)r * H_ + p) * (H_ * H_));
        __bf16* dst = Pperm + (size_t)r * (H_ * H_ * H_);
        const int L = t & 63, quad = L >> 4, lo = L & 15, g0 = t >> 6;

        float4 rg[4][4];                     // all 16 loads in flight at once
#pragma unroll
        for (int s = 0; s < 4; ++s)
#pragma unroll
            for (int it = 0; it < 4; ++it) {
                const int idx = it * 256 + t;
                rg[s][it] = Pp4[(size_t)(s * 32 + (idx >> 5)) * 32 + (idx & 31)];
            }
#pragma unroll
        for (int s = 0; s < 4; ++s) {
            if (s) __syncthreads();
#pragma unroll
            for (int it = 0; it < 4; ++it) {
                const int idx = it * 256 + t;
                float* d = smem + (idx >> 5) * 129 + (idx & 31) * 4;
                d[0] = rg[s][it].x; d[1] = rg[s][it].y;
                d[2] = rg[s][it].z; d[3] = rg[s][it].w;
            }
            __syncthreads();
#pragma unroll
            for (int gg = 0; gg < 2; ++gg) {  // conflict-free reads, emit 16B
                const int g = g0 + 4 * gg;
                __bf16 v8[8];
#pragma unroll
                for (int j = 0; j < 8; ++j)
                    v8[j] = (__bf16)smem[(quad * 8 + j) * 129 + g * 16 + lo];
                *(bf16x8*)(dst + (((size_t)(g * 128 + p) * 4 + s) * 64 + L) * 8) =
                    *(const bf16x8*)v8;
            }
        }
    }
}

// ---------------------------------------------------------------------------
// RANK r (separate dispatch; grid (8 kg, 32 m), 512 thr, 64-row m-tiles).
// vs the 275-µs version: (1) NO global atomics — per-block stats partials
// stored to unique slots partials[s][mblk][col]; consumer reduces 32
// coalesced independent loads. (2) staging vectorized: float4/ushort4 loads
// (4 instead of 16 scalar) with (colgroup,rowslot) mapping -> LDS store
// banks = row (2-way, free) instead of 8-way conflict.
__global__ __launch_bounds__(512, 2)
void k_rank(const __bf16* __restrict__ Pr, const __bf16* __restrict__ Zbf,
            const float* __restrict__ prevT, const float* __restrict__ prevPart,
            const float* __restrict__ gz, const float* __restrict__ bz,
            float* __restrict__ T, float* __restrict__ ownPart, const int first) {
    __shared__ float smem[8960];     // sZin[128][68] | reduce[8*1024]+cs; sAl/sBe tail
    const int kg = blockIdx.x, mblk = blockIdx.y, b0 = mblk * 64;
    const int t = threadIdx.x;
    const int w = t >> 6, L = t & 63, quad = L >> 4, lo = L & 15;

    float* sAl = smem + 8704; float* sBe = smem + 8832;
    // A-frags: 64 rows x K=128 (64 VGPRs)
    bf16x8 A[4][4];
#pragma unroll
    for (int mt = 0; mt < 4; ++mt)
#pragma unroll
        for (int ks = 0; ks < 4; ++ks)
            A[mt][ks] = *(const bf16x8*)(Zbf + (size_t)(b0 + mt * 16 + lo) * H_ + ks * 32 + quad * 8);

    const bf16x8* Pb = (const bf16x8*)Pr;
    const int p0 = w * 16;
    const size_t fbase = ((size_t)kg * 128 + p0) * 4;

#define LOADB(dst, pl) do {                                                   \
    _Pragma("unroll") for (int s_ = 0; s_ < 4; ++s_)                          \
        dst[s_] = Pb[(fbase + (size_t)(pl) * 4 + s_) * 64 + L];               \
} while (0)

    bf16x8 B0[4], B1[4], B2[4], B3[4];
    LOADB(B0, 0);
    LOADB(B1, 1);
    LOADB(B2, 2);
    LOADB(B3, 3);

    if (!first && t < 128) {         // reduce prev-rank partials (coalesced)
        float s1 = 0.f, s2 = 0.f;
#pragma unroll 8
        for (int m = 0; m < 32; ++m) {
            s1 += prevPart[m * 128 + t];
            s2 += prevPart[(32 + m) * 128 + t];
        }
        const float mm = s1 * (1.f / B_);
        const float var = s2 * (1.f / B_) - mm * mm;
        const float a = rsqrtf(var + EPS_) * gz[t];
        sAl[t] = a; sBe[t] = bz[t] - mm * a;
    }
    __syncthreads();
    {   // stage zin -> sZin[col][row] (stride 68); cg=colgroup(4), rs=rowslot
        const int cg = t >> 4, rs = t & 15;
        if (first) {
#pragma unroll
            for (int i = 0; i < 4; ++i) {
                const int row = rs + 16 * i;
                const ushort4 u = *(const ushort4*)(Zbf + (size_t)(b0 + row) * H_ + cg * 4);
                smem[(cg * 4 + 0) * 68 + row] = __uint_as_float((unsigned)u.x << 16);
                smem[(cg * 4 + 1) * 68 + row] = __uint_as_float((unsigned)u.y << 16);
                smem[(cg * 4 + 2) * 68 + row] = __uint_as_float((unsigned)u.z << 16);
                smem[(cg * 4 + 3) * 68 + row] = __uint_as_float((unsigned)u.w << 16);
            }
        } else {
            const float4 al4 = *(const float4*)&sAl[cg * 4];
            const float4 be4 = *(const float4*)&sBe[cg * 4];
#pragma unroll
            for (int i = 0; i < 4; ++i) {
                const int row = rs + 16 * i;
                const float4 v = *(const float4*)(prevT + (size_t)(b0 + row) * H_ + cg * 4);
                smem[(cg * 4 + 0) * 68 + row] = fmaf(v.x, al4.x, be4.x);
                smem[(cg * 4 + 1) * 68 + row] = fmaf(v.y, al4.y, be4.y);
                smem[(cg * 4 + 2) * 68 + row] = fmaf(v.z, al4.z, be4.z);
                smem[(cg * 4 + 3) * 68 + row] = fmaf(v.w, al4.w, be4.w);
            }
        }
    }
    __syncthreads();

    floatx4 acc[4];
#pragma unroll
    for (int mt = 0; mt < 4; ++mt) acc[mt] = (floatx4){0.f, 0.f, 0.f, 0.f};

#define COMPUTE(Bx, pg) do {                                                  \
    floatx4 S_[4];                                                            \
    __builtin_amdgcn_s_setprio(1);                                            \
    _Pragma("unroll") for (int mt_ = 0; mt_ < 4; ++mt_)                       \
        S_[mt_] = __builtin_amdgcn_mfma_f32_16x16x32_bf16(                    \
            A[mt_][0], Bx[0], (floatx4){0.f, 0.f, 0.f, 0.f}, 0, 0, 0);        \
    _Pragma("unroll") for (int ks_ = 1; ks_ < 4; ++ks_)                       \
        _Pragma("unroll") for (int mt_ = 0; mt_ < 4; ++mt_)                   \
            S_[mt_] = __builtin_amdgcn_mfma_f32_16x16x32_bf16(                \
                A[mt_][ks_], Bx[ks_], S_[mt_], 0, 0, 0);                      \
    __builtin_amdgcn_s_setprio(0);                                            \
    _Pragma("unroll") for (int mt_ = 0; mt_ < 4; ++mt_) {                     \
        const floatx4 zi_ =                                                   \
            *(const floatx4*)&smem[(pg) * 68 + mt_ * 16 + quad * 4];          \
        acc[mt_] += zi_ * S_[mt_];                                            \
    }                                                                         \
} while (0)

#pragma unroll
    for (int pp = 0; pp < 16; pp += 4) {
        COMPUTE(B0, p0 + pp);     if (pp < 12) LOADB(B0, pp + 4);
        COMPUTE(B1, p0 + pp + 1); if (pp < 12) LOADB(B1, pp + 5);
        COMPUTE(B2, p0 + pp + 2); if (pp < 12) LOADB(B2, pp + 6);
        COMPUTE(B3, p0 + pp + 3); if (pp < 12) LOADB(B3, pp + 7);
    }
#undef LOADB
#undef COMPUTE

    __syncthreads();                 // sZin dead; reuse for cross-wave p-reduce
#pragma unroll
    for (int mt = 0; mt < 4; ++mt)
#pragma unroll
        for (int i = 0; i < 4; ++i)
            smem[w * 1024 + (mt * 4 + i) * 64 + L] = acc[mt][i];
    if (t < 32) smem[8192 + t] = 0.f;
    __syncthreads();

    float cs = 0.f, cs2 = 0.f;
#pragma unroll
    for (int k2 = 0; k2 < 2; ++k2) {
        const int e = t + 512 * k2;
        float v = 0.f;
#pragma unroll
        for (int q = 0; q < 8; ++q) v += smem[q * 1024 + e];
        const int j = e >> 6, L2 = e & 63;
        const int row = b0 + (j >> 2) * 16 + (L2 >> 4) * 4 + (j & 3);
        const int col = kg * 16 + (L2 & 15);
        T[(size_t)row * H_ + col] = v;
        cs += v; cs2 += v * v;
    }
    cs  += __shfl_xor(cs, 16);  cs  += __shfl_xor(cs, 32);
    cs2 += __shfl_xor(cs2, 16); cs2 += __shfl_xor(cs2, 32);
    if (L < 16) { atomicAdd(&smem[8192 + L], cs); atomicAdd(&smem[8208 + L], cs2); }
    __syncthreads();
    // non-atomic partial store: partials[s][mblk][col]
    if (t < 16)      ownPart[(size_t)mblk * 128 + kg * 16 + t]        = smem[8192 + t];
    else if (t < 32) ownPart[(size_t)(32 + mblk) * 128 + kg * 16 + t - 16] = smem[8192 + t];
}

// ---------------------------------------------------------------------------
// Y = (1/8) sum_r BN_r(T_r); ystats. Grid 64 x 256. Reduces partials itself.
__global__ __launch_bounds__(256)
void k_y(const float* __restrict__ T, const float* __restrict__ partials,
         const float* __restrict__ gz, const float* __restrict__ bz,
         float* __restrict__ Y, float* __restrict__ ysums) {
    __shared__ float al[1024], be[1024], red[256];
    const int bx = blockIdx.x, t = threadIdx.x;
    for (int e = t; e < 1024; e += 256) {
        const int rr = e >> 7, k = e & 127;
        const float* bp = partials + (size_t)rr * 8192;
        float s1 = 0.f, s2 = 0.f;
#pragma unroll 8
        for (int m = 0; m < 32; ++m) {
            s1 += bp[m * 128 + k];
            s2 += bp[(32 + m) * 128 + k];
        }
        const float mm = s1 * (1.f / B_);
        const float var = s2 * (1.f / B_) - mm * mm;
        const float a = rsqrtf(var + EPS_) * gz[k];
        al[e] = a; be[e] = bz[k] - mm * a;
    }
    red[t] = 0.f;
    __syncthreads();
    const int col = t & 127, half = t >> 7;
    float ps = 0.f, ps2 = 0.f;
    for (int i = 0; i < 16; ++i) {
        const int b = bx * 32 + half + 2 * i;
        float y = 0.f;
#pragma unroll
        for (int rr = 0; rr < 8; ++rr)
            y += fmaf(T[(size_t)rr * B_ * H_ + (size_t)b * H_ + col],
                      al[rr * 128 + col], be[rr * 128 + col]);
        y *= (1.f / RANK_);
        Y[(size_t)b * H_ + col] = y;
        ps += y; ps2 += y * y;
    }
    atomicAdd(&red[col],       half == 0 ? ps  : 0.f);
    atomicAdd(&red[128 + col], half == 0 ? ps2 : 0.f);
    __syncthreads();
    atomicAdd(&red[col],       half == 1 ? ps  : 0.f);
    atomicAdd(&red[128 + col], half == 1 ? ps2 : 0.f);
    __syncthreads();
    if (t < 128) {
        atomicAdd(&ysums[t],       red[t]);
        atomicAdd(&ysums[128 + t], red[128 + t]);
    }
}

// ---------------------------------------------------------------------------
// out = relu(relu(BN(Y)@W3 + b3) + R2). Grid 256 x 256, 8 rows per block.
__global__ __launch_bounds__(256)
void k_out(const float* __restrict__ Y, const float* __restrict__ ystats,
           const float* __restrict__ gy, const float* __restrict__ by,
           const float* __restrict__ W3, const float* __restrict__ b3,
           const float* __restrict__ R2, float* __restrict__ out) {
    __shared__ float sy[8 * 132];
    const int bx = blockIdx.x, t = threadIdx.x;
    const int col = t & 127, rh = t >> 7;
    const int b0 = bx * 8;
    const float mm = ystats[col] * (1.f / B_);
    const float var = ystats[128 + col] * (1.f / B_) - mm * mm;
    const float ay = rsqrtf(var + EPS_) * gy[col];
    const float bb = by[col] - mm * ay;
#pragma unroll
    for (int i = 0; i < 4; ++i) {
        const int row = rh + 2 * i;
        sy[row * 132 + col] = fmaf(Y[(size_t)(b0 + row) * H_ + col], ay, bb);
    }
    __syncthreads();
#pragma unroll
    for (int j = 0; j < 4; ++j) {
        const int row = rh * 4 + j;
        float s = 0.f;
        const float* syr = sy + row * 132;
#pragma unroll 8
        for (int h = 0; h < H_; ++h)
            s = fmaf(syr[h], W3[h * H_ + col], s);
        const size_t gi = (size_t)(b0 + row) * H_ + col;
        out[gi] = fmaxf(fmaxf(s + b3[col], 0.f) + R2[gi], 0.f);
    }
}

// ---------------------------------------------------------------------------
extern "C" void kernel_launch(void* const* d_in, const int* in_sizes, int n_in,
                              void* d_out, int out_size, void* d_ws, size_t ws_size,
                              hipStream_t stream) {
    const float* X  = (const float*)d_in[0];
    const float* W1 = (const float*)d_in[1];
    const float* b1 = (const float*)d_in[2];
    const float* W2 = (const float*)d_in[3];
    const float* b2 = (const float*)d_in[4];
    const float* W3 = (const float*)d_in[5];
    const float* b3 = (const float*)d_in[6];
    const float* P  = (const float*)d_in[7];
    const float* gz = (const float*)d_in[8];
    const float* bz = (const float*)d_in[9];
    const float* gy = (const float*)d_in[10];
    const float* by = (const float*)d_in[11];
    float* out = (float*)d_out;

    const size_t rankElems = (size_t)H_ * H_ * H_;

    char* wsb = (char*)d_ws;
    float* R2       = (float*)wsb;   wsb += (size_t)B_ * H_ * 4;
    float* Y        = (float*)wsb;   wsb += (size_t)B_ * H_ * 4;
    float* stats    = (float*)wsb;   wsb += (size_t)(RANK_ + 1) * 256 * 4;  // ysums tail used
    float* partials = (float*)wsb;   wsb += (size_t)RANK_ * 2 * 32 * 128 * 4;
    float* T        = (float*)wsb;   wsb += (size_t)RANK_ * B_ * H_ * 4;
    __bf16* Zbf     = (__bf16*)wsb;  wsb += (size_t)B_ * H_ * 2;
    __bf16* Pperm   = (__bf16*)wsb;

    float* ysums = stats + RANK_ * 256;

    k_head<<<1024, 256, 0, stream>>>(X, W1, b1, W2, b2, P, R2, Zbf, Pperm, stats);

    for (int r = 0; r < RANK_; ++r) {
        const float* prevT = (r == 0) ? (const float*)Zbf : (T + (size_t)(r - 1) * B_ * H_);
        const float* prevP = (r == 0) ? partials : (partials + (size_t)(r - 1) * 8192);
        k_rank<<<dim3(8, 32), 512, 0, stream>>>(Pperm + (size_t)r * rankElems, Zbf,
                                                prevT, prevP, gz, bz,
                                                T + (size_t)r * B_ * H_,
                                                partials + (size_t)r * 8192,
                                                r == 0 ? 1 : 0);
    }

    k_y<<<64, 256, 0, stream>>>(T, partials, gz, bz, Y, ysums);
    k_out<<<256, 256, 0, stream>>>(Y, ysums, gy, by, W3, b3, R2, out);
}

// Round 20
// 282.450 us; speedup vs baseline: 2.5558x; 1.0110x over previous
//
#include <hip/hip_runtime.h>

typedef __bf16 bf16x8 __attribute__((ext_vector_type(8)));
typedef float  floatx4 __attribute__((ext_vector_type(4)));

constexpr int B_    = 2048;
constexpr int NIN   = 256;
constexpr int H_    = 128;
constexpr int RANK_ = 8;
constexpr float EPS_ = 1e-5f;

// ---------------------------------------------------------------------------
// HEAD: zero stats; in_proj on blocks 0..1023 (2 rows each); pconv split into
// (r,p,s) QUARTER-units -> grid 4096, 4 loads/thread, 8 blocks/CU = full
// occupancy (prev: 16 loads/thread, 26% occupancy, 1.65 TB/s latency-bound).
__global__ __launch_bounds__(256)
void k_head(const float* __restrict__ X,
            const float* __restrict__ W1, const float* __restrict__ b1,
            const float* __restrict__ W2, const float* __restrict__ b2,
            const float* __restrict__ P,
            float* __restrict__ R2, __bf16* __restrict__ Zbf,
            __bf16* __restrict__ Pperm, float* __restrict__ stats /* 9*256 */) {
    __shared__ float smem[4160];             // sx[512] / sT[32*129]
    const int bx = blockIdx.x, t = threadIdx.x;

    if (bx < RANK_ + 1) stats[bx * 256 + t] = 0.f;

    if (bx < 1024) {   // in_proj rows bx*2, bx*2+1; thread (col,rh) -> row rh
        const int b0 = bx * 2;
#pragma unroll
        for (int i = 0; i < 2; ++i) {
            const int e = i * 256 + t;
            smem[e] = X[(size_t)(b0 + (e >> 8)) * NIN + (e & 255)];
        }
        __syncthreads();
        const int col = t & 127, rh = t >> 7;
        float s1 = 0.f, s2 = 0.f;
        const float* sx = smem + rh * 256;
#pragma unroll 16
        for (int i = 0; i < NIN; ++i) {
            const float w1 = W1[i * H_ + col];
            const float w2 = W2[i * H_ + col];
            s1 = fmaf(sx[i], w1, s1);  s2 = fmaf(sx[i], w2, s2);
        }
        const int br = b0 + rh;
        const float z = fmaxf(s1 + b1[col], 0.f), r = fmaxf(s2 + b2[col], 0.f);
        Zbf[(size_t)br * H_ + col] = (__bf16)z;  R2[(size_t)br * H_ + col] = r;
        __syncthreads();
    }
    {   // pconv quarter: unit = bx -> (rank r, p, s-chunk)
        const int r = bx >> 9, p = (bx >> 2) & 127, s = bx & 3;
        const float4* Pp4 = (const float4*)(P + ((size_t)r * H_ + p) * (H_ * H_));
        __bf16* dst = Pperm + (size_t)r * (H_ * H_ * H_);
        const int L = t & 63, quad = L >> 4, lo = L & 15, g0 = t >> 6;

        float4 rg[4];                        // 4 loads in flight
#pragma unroll
        for (int it = 0; it < 4; ++it) {
            const int idx = it * 256 + t;
            rg[it] = Pp4[(size_t)(s * 32 + (idx >> 5)) * 32 + (idx & 31)];
        }
#pragma unroll
        for (int it = 0; it < 4; ++it) {
            const int idx = it * 256 + t;
            float* d = smem + (idx >> 5) * 129 + (idx & 31) * 4;
            d[0] = rg[it].x; d[1] = rg[it].y;
            d[2] = rg[it].z; d[3] = rg[it].w;
        }
        __syncthreads();
#pragma unroll
        for (int gg = 0; gg < 2; ++gg) {     // conflict-free reads, emit 16B
            const int g = g0 + 4 * gg;
            __bf16 v8[8];
#pragma unroll
            for (int j = 0; j < 8; ++j)
                v8[j] = (__bf16)smem[(quad * 8 + j) * 129 + g * 16 + lo];
            *(bf16x8*)(dst + (((size_t)(g * 128 + p) * 4 + s) * 64 + L) * 8) =
                *(const bf16x8*)v8;
        }
    }
}

// ---------------------------------------------------------------------------
// RANK r (separate dispatch; grid (8 kg, 32 m), 512 thr, 64-row m-tiles).
// Staging = the 275.2-µs-verified coalesced pattern (r19's vectorized variant
// broke global coalescing: 256B lane stride). Stats via non-atomic partials.
__global__ __launch_bounds__(512, 2)
void k_rank(const __bf16* __restrict__ Pr, const __bf16* __restrict__ Zbf,
            const float* __restrict__ prevT, const float* __restrict__ prevPart,
            const float* __restrict__ gz, const float* __restrict__ bz,
            float* __restrict__ T, float* __restrict__ ownPart, const int first) {
    __shared__ float smem[8960];     // sZin[128][68] | reduce[8*1024]+cs; sAl/sBe tail
    const int kg = blockIdx.x, mblk = blockIdx.y, b0 = mblk * 64;
    const int t = threadIdx.x;
    const int w = t >> 6, L = t & 63, quad = L >> 4, lo = L & 15;

    float* sAl = smem + 8704; float* sBe = smem + 8832;
    // A-frags: 64 rows x K=128 (64 VGPRs)
    bf16x8 A[4][4];
#pragma unroll
    for (int mt = 0; mt < 4; ++mt)
#pragma unroll
        for (int ks = 0; ks < 4; ++ks)
            A[mt][ks] = *(const bf16x8*)(Zbf + (size_t)(b0 + mt * 16 + lo) * H_ + ks * 32 + quad * 8);

    const bf16x8* Pb = (const bf16x8*)Pr;
    const int p0 = w * 16;
    const size_t fbase = ((size_t)kg * 128 + p0) * 4;

#define LOADB(dst, pl) do {                                                   \
    _Pragma("unroll") for (int s_ = 0; s_ < 4; ++s_)                          \
        dst[s_] = Pb[(fbase + (size_t)(pl) * 4 + s_) * 64 + L];               \
} while (0)

    bf16x8 B0[4], B1[4], B2[4], B3[4];
    LOADB(B0, 0);
    LOADB(B1, 1);
    LOADB(B2, 2);
    LOADB(B3, 3);

    if (!first && t < 128) {         // reduce prev-rank partials (coalesced)
        float s1 = 0.f, s2 = 0.f;
#pragma unroll 8
        for (int m = 0; m < 32; ++m) {
            s1 += prevPart[m * 128 + t];
            s2 += prevPart[(32 + m) * 128 + t];
        }
        const float mm = s1 * (1.f / B_);
        const float var = s2 * (1.f / B_) - mm * mm;
        const float a = rsqrtf(var + EPS_) * gz[t];
        sAl[t] = a; sBe[t] = bz[t] - mm * a;
    }
    __syncthreads();
    {   // stage zin -> sZin[p][row] (stride 68) — coalesced global reads
        const int sp = t & 127, rr = t >> 7;     // col, row-quarter
        if (first) {
#pragma unroll
            for (int i = 0; i < 16; ++i) {
                const int row = rr + 4 * i;
                smem[sp * 68 + row] = (float)Zbf[(size_t)(b0 + row) * H_ + sp];
            }
        } else {
            const float a = sAl[sp], be = sBe[sp];
#pragma unroll
            for (int i = 0; i < 16; ++i) {
                const int row = rr + 4 * i;
                smem[sp * 68 + row] = fmaf(prevT[(size_t)(b0 + row) * H_ + sp], a, be);
            }
        }
    }
    __syncthreads();

    floatx4 acc[4];
#pragma unroll
    for (int mt = 0; mt < 4; ++mt) acc[mt] = (floatx4){0.f, 0.f, 0.f, 0.f};

#define COMPUTE(Bx, pg) do {                                                  \
    floatx4 S_[4];                                                            \
    __builtin_amdgcn_s_setprio(1);                                            \
    _Pragma("unroll") for (int mt_ = 0; mt_ < 4; ++mt_)                       \
        S_[mt_] = __builtin_amdgcn_mfma_f32_16x16x32_bf16(                    \
            A[mt_][0], Bx[0], (floatx4){0.f, 0.f, 0.f, 0.f}, 0, 0, 0);        \
    _Pragma("unroll") for (int ks_ = 1; ks_ < 4; ++ks_)                       \
        _Pragma("unroll") for (int mt_ = 0; mt_ < 4; ++mt_)                   \
            S_[mt_] = __builtin_amdgcn_mfma_f32_16x16x32_bf16(                \
                A[mt_][ks_], Bx[ks_], S_[mt_], 0, 0, 0);                      \
    __builtin_amdgcn_s_setprio(0);                                            \
    _Pragma("unroll") for (int mt_ = 0; mt_ < 4; ++mt_) {                     \
        const floatx4 zi_ =                                                   \
            *(const floatx4*)&smem[(pg) * 68 + mt_ * 16 + quad * 4];          \
        acc[mt_] += zi_ * S_[mt_];                                            \
    }                                                                         \
} while (0)

#pragma unroll
    for (int pp = 0; pp < 16; pp += 4) {
        COMPUTE(B0, p0 + pp);     if (pp < 12) LOADB(B0, pp + 4);
        COMPUTE(B1, p0 + pp + 1); if (pp < 12) LOADB(B1, pp + 5);
        COMPUTE(B2, p0 + pp + 2); if (pp < 12) LOADB(B2, pp + 6);
        COMPUTE(B3, p0 + pp + 3); if (pp < 12) LOADB(B3, pp + 7);
    }
#undef LOADB
#undef COMPUTE

    __syncthreads();                 // sZin dead; reuse for cross-wave p-reduce
#pragma unroll
    for (int mt = 0; mt < 4; ++mt)
#pragma unroll
        for (int i = 0; i < 4; ++i)
            smem[w * 1024 + (mt * 4 + i) * 64 + L] = acc[mt][i];
    if (t < 32) smem[8192 + t] = 0.f;
    __syncthreads();

    float cs = 0.f, cs2 = 0.f;
#pragma unroll
    for (int k2 = 0; k2 < 2; ++k2) {
        const int e = t + 512 * k2;
        float v = 0.f;
#pragma unroll
        for (int q = 0; q < 8; ++q) v += smem[q * 1024 + e];
        const int j = e >> 6, L2 = e & 63;
        const int row = b0 + (j >> 2) * 16 + (L2 >> 4) * 4 + (j & 3);
        const int col = kg * 16 + (L2 & 15);
        T[(size_t)row * H_ + col] = v;
        cs += v; cs2 += v * v;
    }
    cs  += __shfl_xor(cs, 16);  cs  += __shfl_xor(cs, 32);
    cs2 += __shfl_xor(cs2, 16); cs2 += __shfl_xor(cs2, 32);
    if (L < 16) { atomicAdd(&smem[8192 + L], cs); atomicAdd(&smem[8208 + L], cs2); }
    __syncthreads();
    // non-atomic partial store: partials[s][mblk][col]
    if (t < 16)      ownPart[(size_t)mblk * 128 + kg * 16 + t]             = smem[8192 + t];
    else if (t < 32) ownPart[(size_t)(32 + mblk) * 128 + kg * 16 + t - 16] = smem[8192 + t];
}

// ---------------------------------------------------------------------------
// Y = (1/8) sum_r BN_r(T_r); ystats. Grid 64 x 256. Reduces partials itself.
__global__ __launch_bounds__(256)
void k_y(const float* __restrict__ T, const float* __restrict__ partials,
         const float* __restrict__ gz, const float* __restrict__ bz,
         float* __restrict__ Y, float* __restrict__ ysums) {
    __shared__ float al[1024], be[1024], red[256];
    const int bx = blockIdx.x, t = threadIdx.x;
    for (int e = t; e < 1024; e += 256) {
        const int rr = e >> 7, k = e & 127;
        const float* bp = partials + (size_t)rr * 8192;
        float s1 = 0.f, s2 = 0.f;
#pragma unroll 8
        for (int m = 0; m < 32; ++m) {
            s1 += bp[m * 128 + k];
            s2 += bp[(32 + m) * 128 + k];
        }
        const float mm = s1 * (1.f / B_);
        const float var = s2 * (1.f / B_) - mm * mm;
        const float a = rsqrtf(var + EPS_) * gz[k];
        al[e] = a; be[e] = bz[k] - mm * a;
    }
    red[t] = 0.f;
    __syncthreads();
    const int col = t & 127, half = t >> 7;
    float ps = 0.f, ps2 = 0.f;
    for (int i = 0; i < 16; ++i) {
        const int b = bx * 32 + half + 2 * i;
        float y = 0.f;
#pragma unroll
        for (int rr = 0; rr < 8; ++rr)
            y += fmaf(T[(size_t)rr * B_ * H_ + (size_t)b * H_ + col],
                      al[rr * 128 + col], be[rr * 128 + col]);
        y *= (1.f / RANK_);
        Y[(size_t)b * H_ + col] = y;
        ps += y; ps2 += y * y;
    }
    atomicAdd(&red[col],       half == 0 ? ps  : 0.f);
    atomicAdd(&red[128 + col], half == 0 ? ps2 : 0.f);
    __syncthreads();
    atomicAdd(&red[col],       half == 1 ? ps  : 0.f);
    atomicAdd(&red[128 + col], half == 1 ? ps2 : 0.f);
    __syncthreads();
    if (t < 128) {
        atomicAdd(&ysums[t],       red[t]);
        atomicAdd(&ysums[128 + t], red[128 + t]);
    }
}

// ---------------------------------------------------------------------------
// out = relu(relu(BN(Y)@W3 + b3) + R2). Grid 256 x 256, 8 rows per block.
__global__ __launch_bounds__(256)
void k_out(const float* __restrict__ Y, const float* __restrict__ ystats,
           const float* __restrict__ gy, const float* __restrict__ by,
           const float* __restrict__ W3, const float* __restrict__ b3,
           const float* __restrict__ R2, float* __restrict__ out) {
    __shared__ float sy[8 * 132];
    const int bx = blockIdx.x, t = threadIdx.x;
    const int col = t & 127, rh = t >> 7;
    const int b0 = bx * 8;
    const float mm = ystats[col] * (1.f / B_);
    const float var = ystats[128 + col] * (1.f / B_) - mm * mm;
    const float ay = rsqrtf(var + EPS_) * gy[col];
    const float bb = by[col] - mm * ay;
#pragma unroll
    for (int i = 0; i < 4; ++i) {
        const int row = rh + 2 * i;
        sy[row * 132 + col] = fmaf(Y[(size_t)(b0 + row) * H_ + col], ay, bb);
    }
    __syncthreads();
#pragma unroll
    for (int j = 0; j < 4; ++j) {
        const int row = rh * 4 + j;
        float s = 0.f;
        const float* syr = sy + row * 132;
#pragma unroll 8
        for (int h = 0; h < H_; ++h)
            s = fmaf(syr[h], W3[h * H_ + col], s);
        const size_t gi = (size_t)(b0 + row) * H_ + col;
        out[gi] = fmaxf(fmaxf(s + b3[col], 0.f) + R2[gi], 0.f);
    }
}

// ---------------------------------------------------------------------------
extern "C" void kernel_launch(void* const* d_in, const int* in_sizes, int n_in,
                              void* d_out, int out_size, void* d_ws, size_t ws_size,
                              hipStream_t stream) {
    const float* X  = (const float*)d_in[0];
    const float* W1 = (const float*)d_in[1];
    const float* b1 = (const float*)d_in[2];
    const float* W2 = (const float*)d_in[3];
    const float* b2 = (const float*)d_in[4];
    const float* W3 = (const float*)d_in[5];
    const float* b3 = (const float*)d_in[6];
    const float* P  = (const float*)d_in[7];
    const float* gz = (const float*)d_in[8];
    const float* bz = (const float*)d_in[9];
    const float* gy = (const float*)d_in[10];
    const float* by = (const float*)d_in[11];
    float* out = (float*)d_out;

    const size_t rankElems = (size_t)H_ * H_ * H_;

    char* wsb = (char*)d_ws;
    float* R2       = (float*)wsb;   wsb += (size_t)B_ * H_ * 4;
    float* Y        = (float*)wsb;   wsb += (size_t)B_ * H_ * 4;
    float* stats    = (float*)wsb;   wsb += (size_t)(RANK_ + 1) * 256 * 4;  // ysums tail used
    float* partials = (float*)wsb;   wsb += (size_t)RANK_ * 2 * 32 * 128 * 4;
    float* T        = (float*)wsb;   wsb += (size_t)RANK_ * B_ * H_ * 4;
    __bf16* Zbf     = (__bf16*)wsb;  wsb += (size_t)B_ * H_ * 2;
    __bf16* Pperm   = (__bf16*)wsb;

    float* ysums = stats + RANK_ * 256;

    k_head<<<4096, 256, 0, stream>>>(X, W1, b1, W2, b2, P, R2, Zbf, Pperm, stats);

    for (int r = 0; r < RANK_; ++r) {
        const float* prevT = (r == 0) ? (const float*)Zbf : (T + (size_t)(r - 1) * B_ * H_);
        const float* prevP = (r == 0) ? partials : (partials + (size_t)(r - 1) * 8192);
        k_rank<<<dim3(8, 32), 512, 0, stream>>>(Pperm + (size_t)r * rankElems, Zbf,
                                                prevT, prevP, gz, bz,
                                                T + (size_t)r * B_ * H_,
                                                partials + (size_t)r * 8192,
                                                r == 0 ? 1 : 0);
    }

    k_y<<<64, 256, 0, stream>>>(T, partials, gz, bz, Y, ysums);
    k_out<<<256, 256, 0, stream>>>(Y, ysums, gy, by, W3, b3, R2, out);
}